// Round 6
// baseline (1609.587 us; speedup 1.0000x reference)
//
#include <hip/hip_runtime.h>
#include <hip/hip_bf16.h>

typedef __attribute__((ext_vector_type(8))) short short8;      // 8 x bf16 (4 VGPR)
typedef __attribute__((ext_vector_type(4))) float f32x4;       // MFMA acc
typedef __attribute__((ext_vector_type(4))) unsigned int u32x4;

#define NGRP 8          // src slices
#define BKT 64          // nodes per dst bucket
#define CAP 448         // records per (slice,bucket) region; mean 256, ~12 sigma margin

static __device__ __forceinline__ unsigned short f2b(float f) {
  unsigned int u = __builtin_bit_cast(unsigned int, f);
  u = (u + 0x7fffu + ((u >> 16) & 1u)) >> 16;   // RNE
  return (unsigned short)u;
}
static __device__ __forceinline__ float b2f(unsigned short h) {
  unsigned int u = ((unsigned int)h) << 16;
  return __builtin_bit_cast(float, u);
}

// ---------------- edge dtype detection ----------------
__global__ void detect_kernel(const int* __restrict__ ew, int* __restrict__ flag) {
  if (threadIdx.x == 0 && blockIdx.x == 0) {
    int z = 0;
#pragma unroll
    for (int i = 1; i < 32; i += 2) z |= ew[i];
    *flag = (z == 0) ? 1 : 0;   // 1 => int64
  }
}

// ---------------- fused: deg8 histogram + src-slice bucket staging ----------
__global__ __launch_bounds__(256) void stage_kernel(
    const int* __restrict__ ew, int ne, const int* __restrict__ flag,
    int* __restrict__ deg8, int* __restrict__ bcnt,
    unsigned int* __restrict__ stag, int nb, int n, int sdiv) {
  const int e = blockIdx.x * 256 + threadIdx.x;
  if (e >= ne) return;
  const int gx = blockIdx.x & (NGRP - 1);    // XCD shard for degree histogram
  const int is64 = *flag;
  int s, d;
  if (is64) {
    s = ew[2 * (size_t)e];
    d = ew[(size_t)2 * ne + 2 * (size_t)e];
  } else {
    s = ew[e];
    d = ew[(size_t)ne + e];
  }
  atomicAdd(&deg8[(size_t)gx * n + d], 1);
  const int gs = (unsigned)s / (unsigned)sdiv;   // src slice 0..7
  const int b = d >> 6;                          // dst bucket
  const unsigned loc = (unsigned)(d & (BKT - 1));
  int pos = atomicAdd(&bcnt[((size_t)gs * nb + b) * 16], 1);   // 64B-padded counter
  if (pos < CAP)
    stag[((size_t)gs * nb + b) * CAP + pos] = (loc << 17) | (unsigned)s;
}

// ---------------- dinv[i] = rsqrt(1 + sum_g deg8[g][i]) ----------------
__global__ __launch_bounds__(256) void dinv_kernel(const int* __restrict__ deg8,
                                                   float* __restrict__ dinv, int n) {
  int i = blockIdx.x * 256 + threadIdx.x;
  if (i >= n) return;
  int d = 1;
#pragma unroll
  for (int g = 0; g < NGRP; ++g) d += deg8[(size_t)g * n + i];
  dinv[i] = rsqrtf((float)d);
}

// ---------------- W_gcn^T cast to bf16: Wt[c][k], c<64, k<512 ----------------
__global__ __launch_bounds__(256) void wt_kernel(const float* __restrict__ Wg,
                                                 unsigned short* __restrict__ Wt) {
  int t = blockIdx.x * 256 + threadIdx.x;   // 32768 total
  int k = t >> 6, c = t & 63;
  Wt[c * 512 + k] = f2b(Wg[t]);             // Wg[k*64 + c]
}

// ------- hs = (bf16(x) @ bf16(W)) * dinv[row]  via MFMA, stored bf16 --------
__global__ __launch_bounds__(256) void gemm_kernel(const float* __restrict__ x,
                                                   const unsigned short* __restrict__ Wt,
                                                   const float* __restrict__ dinv,
                                                   unsigned short* __restrict__ hbf,
                                                   int nnodes) {
  __shared__ unsigned short Bt[64][40];
  const int tid = threadIdx.x;
  const int lane = tid & 63;
  const int wv = tid >> 6;
  const int l15 = lane & 15;
  const int hi = lane >> 4;
  const int rowbase = blockIdx.x * 128 + wv * 32;

  f32x4 acc[2][4] = {};

  for (int kc = 0; kc < 16; ++kc) {
    const int k0 = kc * 32;
    {
      int c = tid >> 2, seg = tid & 3;
      u32x4 v = *reinterpret_cast<const u32x4*>(Wt + c * 512 + k0 + seg * 8);
      *reinterpret_cast<u32x4*>(&Bt[c][seg * 8]) = v;
    }
    __syncthreads();

    short8 afrag[2];
#pragma unroll
    for (int i = 0; i < 2; ++i) {
      int row = rowbase + i * 16 + l15;
      row = row < nnodes ? row : nnodes - 1;
      const float* p = x + (size_t)row * 512 + k0 + hi * 8;
      f32x4 f0 = *reinterpret_cast<const f32x4*>(p);
      f32x4 f1 = *reinterpret_cast<const f32x4*>(p + 4);
      short8 a;
      a[0] = (short)f2b(f0[0]); a[1] = (short)f2b(f0[1]);
      a[2] = (short)f2b(f0[2]); a[3] = (short)f2b(f0[3]);
      a[4] = (short)f2b(f1[0]); a[5] = (short)f2b(f1[1]);
      a[6] = (short)f2b(f1[2]); a[7] = (short)f2b(f1[3]);
      afrag[i] = a;
    }
#pragma unroll
    for (int j = 0; j < 4; ++j) {
      short8 b = *reinterpret_cast<const short8*>(&Bt[j * 16 + l15][hi * 8]);
      acc[0][j] = __builtin_amdgcn_mfma_f32_16x16x32_bf16(afrag[0], b, acc[0][j], 0, 0, 0);
      acc[1][j] = __builtin_amdgcn_mfma_f32_16x16x32_bf16(afrag[1], b, acc[1][j], 0, 0, 0);
    }
    __syncthreads();
  }

#pragma unroll
  for (int i = 0; i < 2; ++i)
#pragma unroll
    for (int r = 0; r < 4; ++r) {
      int row = rowbase + i * 16 + hi * 4 + r;
      if (row < nnodes) {
        float dv = dinv[row];
#pragma unroll
        for (int j = 0; j < 4; ++j)
          hbf[(size_t)row * 64 + j * 16 + l15] = f2b(acc[i][j][r] * dv);
      }
    }
}

// ---------------- bucket aggregation via async DMA staging ----------------
// one block per 64-node dst bucket. Per wave-chunk of 32 records: 4x
// global_load_lds (fire-and-forget, HW vmcnt FIFO) stage 32 h-rows into LDS,
// one vmcnt(0) drain, then LDS-only accumulate. MLP is structural.
__global__ __launch_bounds__(256) void agg4_kernel(
    const unsigned short* __restrict__ hbf, const unsigned int* __restrict__ stag,
    const int* __restrict__ bcnt, const float* __restrict__ dinv,
    const float* __restrict__ b_gcn, const float* __restrict__ W_cls,
    const float* __restrict__ b_cls, float* __restrict__ out, int nb, int n) {
  __shared__ float acc[BKT][64];                 // 16 KB
  __shared__ unsigned recs[CAP];                 // 1.75 KB
  __shared__ unsigned short rows[4][32][64];     // 16 KB staging (per-wave 32 rows)
  const int tid = threadIdx.x;
  const int lane = tid & 63;
  const int wv = tid >> 6;
  const int b = blockIdx.x;

  float* af = &acc[0][0];
#pragma unroll
  for (int i = 0; i < 16; ++i) af[i * 256 + tid] = 0.f;

  float wcls[7], bcl[7];
#pragma unroll
  for (int c = 0; c < 7; ++c) wcls[c] = W_cls[lane * 7 + c];
#pragma unroll
  for (int c = 0; c < 7; ++c) bcl[c] = b_cls[c];
  const float bg = b_gcn[lane];
  __syncthreads();

#pragma unroll 1
  for (int g = 0; g < NGRP; ++g) {
    int cnt = bcnt[((size_t)g * nb + b) * 16];
    cnt = cnt < CAP ? cnt : CAP;
    const unsigned int* rg = stag + ((size_t)g * nb + b) * CAP;
    // cooperative record staging (coalesced)
    for (int i = tid; i < cnt; i += 256) recs[i] = rg[i];
    __syncthreads();

#pragma unroll 1
    for (int base = wv * 32; base < cnt; base += 128) {
      int m = cnt - base;
      m = m < 32 ? m : 32;
      // issue up to 4 async DMAs; each stages 8 rows (8 lanes x 16B per row)
#pragma unroll
      for (int j = 0; j < 32; j += 8) {
        if (j < m) {
          int idx = base + j + (lane >> 3);
          if (idx >= cnt) idx = base;              // dup row for tail slots
          unsigned rr = recs[idx];
          int src = (int)(rr & 0x1FFFFu);
          const unsigned short* ga = hbf + (size_t)src * 64 + (lane & 7) * 8;
          __builtin_amdgcn_global_load_lds(
              (const __attribute__((address_space(1))) void*)ga,
              (__attribute__((address_space(3))) void*)&rows[wv][j][0],
              16, 0, 0);
        }
      }
      asm volatile("s_waitcnt vmcnt(0)" ::: "memory");
      // LDS-only accumulate
#pragma unroll 1
      for (int j = 0; j < m; ++j) {
        unsigned rec = recs[base + j];
        int loc = (int)(rec >> 17);
        float v = b2f(rows[wv][j][lane]);
        atomicAdd(&acc[loc][lane], v);
      }
      // ensure all LDS reads of rows retired before next chunk's DMA overwrites
      asm volatile("s_waitcnt lgkmcnt(0)" ::: "memory");
    }
    __syncthreads();   // recs reused next slice
  }

  // epilogue: 16 nodes per wave; self term = hs[node] (pre-scaled by dinv)
  for (int r = wv; r < BKT; r += 4) {
    int node = b * BKT + r;
    if (node >= n) break;
    float dn = dinv[node];
    float self = b2f(hbf[(size_t)node * 64 + lane]);
    float h2 = fmaf(dn, acc[r][lane] + self, bg);
    h2 = h2 > 0.f ? h2 : 0.f;
    float p[7];
#pragma unroll
    for (int c = 0; c < 7; ++c) p[c] = h2 * wcls[c];
#pragma unroll
    for (int off = 32; off; off >>= 1) {
#pragma unroll
      for (int c = 0; c < 7; ++c) p[c] += __shfl_xor(p[c], off, 64);
    }
    if (lane == 0) {
      float* o = out + (size_t)node * 7;
#pragma unroll
      for (int c = 0; c < 7; ++c) o[c] = p[c] + bcl[c];
    }
  }
}

// =================== fallback path (small workspace) =========================
__global__ __launch_bounds__(256) void init_deg_kernel(int* __restrict__ deg, int n) {
  int i = blockIdx.x * 256 + threadIdx.x;
  if (i < n) deg[i] = 1;
}
__global__ __launch_bounds__(256) void deg_kernel(const int* __restrict__ ew, int ne,
                                                  const int* __restrict__ flag,
                                                  int* __restrict__ deg) {
  int e = blockIdx.x * 256 + threadIdx.x;
  if (e >= ne) return;
  const int is64 = *flag;
  int d = is64 ? ew[(size_t)2 * ne + 2 * (size_t)e] : ew[(size_t)ne + e];
  atomicAdd(&deg[d], 1);
}
__global__ __launch_bounds__(256) void partial_kernel(const int* __restrict__ deg,
                                                      int* __restrict__ part, int n) {
  int i = blockIdx.x * 256 + threadIdx.x;
  int v = (i < n) ? deg[i] - 1 : 0;
#pragma unroll
  for (int off = 32; off; off >>= 1) v += __shfl_xor(v, off, 64);
  __shared__ int w[4];
  if ((threadIdx.x & 63) == 0) w[threadIdx.x >> 6] = v;
  __syncthreads();
  if (threadIdx.x == 0) part[blockIdx.x] = w[0] + w[1] + w[2] + w[3];
}
__global__ __launch_bounds__(512) void scanpart_kernel(int* __restrict__ part, int nb) {
  __shared__ int sh[512];
  int t = threadIdx.x;
  int v = (t < nb) ? part[t] : 0;
  sh[t] = v;
  __syncthreads();
  for (int off = 1; off < 512; off <<= 1) {
    int u = (t >= off) ? sh[t - off] : 0;
    __syncthreads();
    sh[t] += u;
    __syncthreads();
  }
  if (t < nb) part[t] = sh[t] - v;
}
__global__ __launch_bounds__(256) void fill_kernel(const int* __restrict__ deg,
                                                   const int* __restrict__ part,
                                                   int* __restrict__ rowptr,
                                                   int* __restrict__ cursor,
                                                   float* __restrict__ dinv, int n) {
  __shared__ int sh[256];
  int i = blockIdx.x * 256 + threadIdx.x;
  int d = (i < n) ? deg[i] : 1;
  int v = d - 1;
  sh[threadIdx.x] = v;
  __syncthreads();
  for (int off = 1; off < 256; off <<= 1) {
    int t = (threadIdx.x >= off) ? sh[threadIdx.x - off] : 0;
    __syncthreads();
    sh[threadIdx.x] += t;
    __syncthreads();
  }
  int incl = sh[threadIdx.x];
  int excl = incl - v;
  int base = part[blockIdx.x];
  if (i < n) {
    rowptr[i] = base + excl;
    cursor[i] = base + excl;
    dinv[i] = rsqrtf((float)d);
    if (i == n - 1) rowptr[n] = base + incl;
  }
}
__global__ __launch_bounds__(256) void scatter_kernel(const int* __restrict__ ew, int ne,
                                                      const int* __restrict__ flag,
                                                      int* __restrict__ cursor,
                                                      int* __restrict__ csr_src) {
  int e = blockIdx.x * 256 + threadIdx.x;
  if (e >= ne) return;
  const int is64 = *flag;
  int s, d;
  if (is64) {
    s = ew[2 * (size_t)e];
    d = ew[(size_t)2 * ne + 2 * (size_t)e];
  } else {
    s = ew[e];
    d = ew[(size_t)ne + e];
  }
  int pos = atomicAdd(&cursor[d], 1);
  csr_src[pos] = s;
}
// fallback agg: hbf is PRE-SCALED (hs = h*dinv[src])
__global__ __launch_bounds__(256) void agg_kernel(const unsigned short* __restrict__ hbf,
                                                  const int* __restrict__ rowptr,
                                                  const int* __restrict__ csr_src,
                                                  const float* __restrict__ dinv,
                                                  const float* __restrict__ b_gcn,
                                                  const float* __restrict__ W_cls,
                                                  const float* __restrict__ b_cls,
                                                  float* __restrict__ out, int n) {
  const int lane = threadIdx.x & 63;
  const int node = blockIdx.x * 4 + (threadIdx.x >> 6);
  if (node >= n) return;
  const float dn = dinv[node];
  float inner = 0.f;
  const int e0 = rowptr[node], e1 = rowptr[node + 1];
  for (int e = e0; e < e1; ++e) {
    int s = csr_src[e];
    inner += b2f(hbf[(size_t)s * 64 + lane]);
  }
  float self = b2f(hbf[(size_t)node * 64 + lane]);
  float h2 = fmaf(dn, inner + self, b_gcn[lane]);
  h2 = h2 > 0.f ? h2 : 0.f;
  float p[7];
#pragma unroll
  for (int c = 0; c < 7; ++c) p[c] = h2 * W_cls[lane * 7 + c];
#pragma unroll
  for (int off = 32; off; off >>= 1) {
#pragma unroll
    for (int c = 0; c < 7; ++c) p[c] += __shfl_xor(p[c], off, 64);
  }
  if (lane == 0) {
    float* o = out + (size_t)node * 7;
#pragma unroll
    for (int c = 0; c < 7; ++c) o[c] = p[c] + b_cls[c];
  }
}

extern "C" void kernel_launch(void* const* d_in, const int* in_sizes, int n_in,
                              void* d_out, int out_size, void* d_ws, size_t ws_size,
                              hipStream_t stream) {
  const float* x = (const float*)d_in[0];
  const int* ew = (const int*)d_in[1];
  const float* W_gcn = (const float*)d_in[2];
  const float* b_gcn = (const float*)d_in[3];
  const float* W_cls = (const float*)d_in[4];
  const float* b_cls = (const float*)d_in[5];
  float* out = (float*)d_out;

  const int N = in_sizes[0] / 512;              // 100000
  const int NE = in_sizes[1] / 2;               // 3200000
  const int NB = (N + BKT - 1) / BKT;           // 1563

  size_t off = 0;
  auto take = [&](size_t b) { size_t o = off; off += (b + 255) & ~(size_t)255; return o; };
  char* ws = (char*)d_ws;
  int* flag            = (int*)(ws + take(sizeof(int)));
  unsigned short* Wt   = (unsigned short*)(ws + take((size_t)512 * 64 * 2));
  float* dinv          = (float*)(ws + take((size_t)N * 4));
  unsigned short* hbf  = (unsigned short*)(ws + take((size_t)N * 64 * 2));
  const size_t common_off = off;
  size_t deg8_bytes    = (size_t)NGRP * N * 4;
  int* deg8            = (int*)(ws + take(deg8_bytes));
  size_t bcnt_bytes    = (size_t)NGRP * NB * 16 * 4;
  int* bcnt            = (int*)(ws + take(bcnt_bytes));
  unsigned int* stag   = (unsigned int*)(ws + take((size_t)NGRP * NB * CAP * 4));
  const bool big = off <= ws_size;

  const int nbN = (N + 255) / 256;
  const int nbE = (NE + 255) / 256;
  const int sdiv = (N + NGRP - 1) / NGRP;       // 12500 src nodes per slice

  if (big) {
    detect_kernel<<<1, 64, 0, stream>>>(ew, flag);
    hipMemsetAsync(deg8, 0, deg8_bytes, stream);
    hipMemsetAsync(bcnt, 0, bcnt_bytes, stream);
    stage_kernel<<<nbE, 256, 0, stream>>>(ew, NE, flag, deg8, bcnt, stag, NB, N, sdiv);
    dinv_kernel<<<nbN, 256, 0, stream>>>(deg8, dinv, N);
    wt_kernel<<<128, 256, 0, stream>>>(W_gcn, Wt);
    gemm_kernel<<<(N + 127) / 128, 256, 0, stream>>>(x, Wt, dinv, hbf, N);
    agg4_kernel<<<NB, 256, 0, stream>>>(hbf, stag, bcnt, dinv, b_gcn, W_cls, b_cls,
                                        out, NB, N);
  } else {
    off = common_off;
    int* cursor   = (int*)(ws + take((size_t)N * 4));
    int* rowptr   = (int*)(ws + take(((size_t)N + 1) * 4));
    int* csr_src  = (int*)(ws + take((size_t)NE * 4));
    int* part     = (int*)(ws + take((size_t)512 * 4));
    detect_kernel<<<1, 64, 0, stream>>>(ew, flag);
    init_deg_kernel<<<nbN, 256, 0, stream>>>(cursor, N);
    deg_kernel<<<nbE, 256, 0, stream>>>(ew, NE, flag, cursor);
    partial_kernel<<<nbN, 256, 0, stream>>>(cursor, part, N);
    scanpart_kernel<<<1, 512, 0, stream>>>(part, nbN);
    fill_kernel<<<nbN, 256, 0, stream>>>(cursor, part, rowptr, cursor, dinv, N);
    scatter_kernel<<<nbE, 256, 0, stream>>>(ew, NE, flag, cursor, csr_src);
    wt_kernel<<<128, 256, 0, stream>>>(W_gcn, Wt);
    gemm_kernel<<<(N + 127) / 128, 256, 0, stream>>>(x, Wt, dinv, hbf, N);
    agg_kernel<<<(N + 3) / 4, 256, 0, stream>>>(hbf, rowptr, csr_src, dinv,
                                                b_gcn, W_cls, b_cls, out, N);
  }
}

// Round 7
// 433.336 us; speedup vs baseline: 3.7144x; 3.7144x over previous
//
#include <hip/hip_runtime.h>
#include <hip/hip_bf16.h>

typedef __attribute__((ext_vector_type(8))) short short8;      // 8 x bf16 (4 VGPR)
typedef __attribute__((ext_vector_type(4))) float f32x4;       // MFMA acc
typedef __attribute__((ext_vector_type(4))) unsigned int u32x4;

static __device__ __forceinline__ unsigned short f2b(float f) {
  unsigned int u = __builtin_bit_cast(unsigned int, f);
  u = (u + 0x7fffu + ((u >> 16) & 1u)) >> 16;   // RNE
  return (unsigned short)u;
}
static __device__ __forceinline__ float b2f(unsigned short h) {
  unsigned int u = ((unsigned int)h) << 16;
  return __builtin_bit_cast(float, u);
}

// ---------------- edge dtype detection ----------------
__global__ void detect_kernel(const int* __restrict__ ew, int* __restrict__ flag) {
  if (threadIdx.x == 0 && blockIdx.x == 0) {
    int z = 0;
#pragma unroll
    for (int i = 1; i < 32; i += 2) z |= ew[i];
    *flag = (z == 0) ? 1 : 0;   // 1 => int64
  }
}

// ---------------- XCD-sharded degree histogram (ng copies) ----------------
// g = blockIdx % ng: each histogram copy's dirty lines stay in ONE XCD's L2.
__global__ __launch_bounds__(256) void deg8_kernel(const int* __restrict__ ew, int ne,
                                                   const int* __restrict__ flag,
                                                   int* __restrict__ deg8, int n, int ng) {
  int e = blockIdx.x * 256 + threadIdx.x;
  if (e >= ne) return;
  const int gx = blockIdx.x & (ng - 1);
  const int is64 = *flag;
  int d = is64 ? ew[(size_t)2 * ne + 2 * (size_t)e] : ew[(size_t)ne + e];
  atomicAdd(&deg8[(size_t)gx * n + d], 1);
}

// ---------------- edeg[i] = sum_g deg8[g][i];  dinv[i] = rsqrt(1+edeg) -------
__global__ __launch_bounds__(256) void dinvsum_kernel(const int* __restrict__ deg8,
                                                      float* __restrict__ dinv,
                                                      int* __restrict__ edeg,
                                                      int n, int ng) {
  int i = blockIdx.x * 256 + threadIdx.x;
  if (i >= n) return;
  int d = 0;
  for (int g = 0; g < ng; ++g) d += deg8[(size_t)g * n + i];
  edeg[i] = d;
  dinv[i] = rsqrtf((float)(1 + d));
}

// ---------------- parallel scan: block partials of edeg ----------------
__global__ __launch_bounds__(256) void partial_kernel(const int* __restrict__ edeg,
                                                      int* __restrict__ part, int n) {
  int i = blockIdx.x * 256 + threadIdx.x;
  int v = (i < n) ? edeg[i] : 0;
#pragma unroll
  for (int off = 32; off; off >>= 1) v += __shfl_xor(v, off, 64);
  __shared__ int w[4];
  if ((threadIdx.x & 63) == 0) w[threadIdx.x >> 6] = v;
  __syncthreads();
  if (threadIdx.x == 0) part[blockIdx.x] = w[0] + w[1] + w[2] + w[3];
}

// ---------------- parallel scan: scan the partials (1 block) ----------------
__global__ __launch_bounds__(512) void scanpart_kernel(int* __restrict__ part, int nb) {
  __shared__ int sh[512];
  int t = threadIdx.x;
  int v = (t < nb) ? part[t] : 0;
  sh[t] = v;
  __syncthreads();
  for (int off = 1; off < 512; off <<= 1) {
    int u = (t >= off) ? sh[t - off] : 0;
    __syncthreads();
    sh[t] += u;
    __syncthreads();
  }
  if (t < nb) part[t] = sh[t] - v;   // exclusive
}

// ---------------- parallel scan: fill rowptr/cursor ----------------
__global__ __launch_bounds__(256) void fill_kernel(const int* __restrict__ edeg,
                                                   const int* __restrict__ part,
                                                   int* __restrict__ rowptr,
                                                   int* __restrict__ cursor, int n) {
  __shared__ int sh[256];
  int i = blockIdx.x * 256 + threadIdx.x;
  int v = (i < n) ? edeg[i] : 0;
  sh[threadIdx.x] = v;
  __syncthreads();
  for (int off = 1; off < 256; off <<= 1) {
    int t = (threadIdx.x >= off) ? sh[threadIdx.x - off] : 0;
    __syncthreads();
    sh[threadIdx.x] += t;
    __syncthreads();
  }
  int incl = sh[threadIdx.x];
  int excl = incl - v;
  int base = part[blockIdx.x];
  if (i < n) {
    rowptr[i] = base + excl;
    cursor[i] = base + excl;
    if (i == n - 1) rowptr[n] = base + incl;
  }
}

// ---------------- XCD-sliced scatter: ng passes over edges ------------------
// group g keeps only dst in slice g -> csr_src region and cursors for that
// slice are written by ONE XCD: dirty lines don't bounce. Edge re-reads are
// sequential and L3-served (cheap).
__global__ __launch_bounds__(256) void scatter8_kernel(const int* __restrict__ ew, int ne,
                                                       const int* __restrict__ flag,
                                                       int* __restrict__ cursor,
                                                       int* __restrict__ csr_src,
                                                       int sdiv, int ng) {
  const int g = blockIdx.x & (ng - 1);
  int e = (blockIdx.x >> (ng == 8 ? 3 : 0)) * 256 + threadIdx.x;
  if (ng == 1) e = blockIdx.x * 256 + threadIdx.x;
  if (e >= ne) return;
  const int is64 = *flag;
  int s, d;
  if (is64) {
    s = ew[2 * (size_t)e];
    d = ew[(size_t)2 * ne + 2 * (size_t)e];
  } else {
    s = ew[e];
    d = ew[(size_t)ne + e];
  }
  if ((int)((unsigned)d / (unsigned)sdiv) != g) return;
  int pos = atomicAdd(&cursor[d], 1);
  csr_src[pos] = s;
}

// ---------------- W_gcn^T cast to bf16: Wt[c][k], c<64, k<512 ----------------
__global__ __launch_bounds__(256) void wt_kernel(const float* __restrict__ Wg,
                                                 unsigned short* __restrict__ Wt) {
  int t = blockIdx.x * 256 + threadIdx.x;   // 32768 total
  int k = t >> 6, c = t & 63;
  Wt[c * 512 + k] = f2b(Wg[t]);             // Wg[k*64 + c]
}

// ------- hs = (bf16(x) @ bf16(W)) * dinv[row]  via MFMA, stored bf16 --------
__global__ __launch_bounds__(256) void gemm_kernel(const float* __restrict__ x,
                                                   const unsigned short* __restrict__ Wt,
                                                   const float* __restrict__ dinv,
                                                   unsigned short* __restrict__ hbf,
                                                   int nnodes) {
  __shared__ unsigned short Bt[64][40];
  const int tid = threadIdx.x;
  const int lane = tid & 63;
  const int wv = tid >> 6;
  const int l15 = lane & 15;
  const int hi = lane >> 4;
  const int rowbase = blockIdx.x * 128 + wv * 32;

  f32x4 acc[2][4] = {};

  for (int kc = 0; kc < 16; ++kc) {
    const int k0 = kc * 32;
    {
      int c = tid >> 2, seg = tid & 3;
      u32x4 v = *reinterpret_cast<const u32x4*>(Wt + c * 512 + k0 + seg * 8);
      *reinterpret_cast<u32x4*>(&Bt[c][seg * 8]) = v;
    }
    __syncthreads();

    short8 afrag[2];
#pragma unroll
    for (int i = 0; i < 2; ++i) {
      int row = rowbase + i * 16 + l15;
      row = row < nnodes ? row : nnodes - 1;
      const float* p = x + (size_t)row * 512 + k0 + hi * 8;
      f32x4 f0 = *reinterpret_cast<const f32x4*>(p);
      f32x4 f1 = *reinterpret_cast<const f32x4*>(p + 4);
      short8 a;
      a[0] = (short)f2b(f0[0]); a[1] = (short)f2b(f0[1]);
      a[2] = (short)f2b(f0[2]); a[3] = (short)f2b(f0[3]);
      a[4] = (short)f2b(f1[0]); a[5] = (short)f2b(f1[1]);
      a[6] = (short)f2b(f1[2]); a[7] = (short)f2b(f1[3]);
      afrag[i] = a;
    }
#pragma unroll
    for (int j = 0; j < 4; ++j) {
      short8 b = *reinterpret_cast<const short8*>(&Bt[j * 16 + l15][hi * 8]);
      acc[0][j] = __builtin_amdgcn_mfma_f32_16x16x32_bf16(afrag[0], b, acc[0][j], 0, 0, 0);
      acc[1][j] = __builtin_amdgcn_mfma_f32_16x16x32_bf16(afrag[1], b, acc[1][j], 0, 0, 0);
    }
    __syncthreads();
  }

#pragma unroll
  for (int i = 0; i < 2; ++i)
#pragma unroll
    for (int r = 0; r < 4; ++r) {
      int row = rowbase + i * 16 + hi * 4 + r;
      if (row < nnodes) {
        float dv = dinv[row];
#pragma unroll
        for (int j = 0; j < 4; ++j)
          hbf[(size_t)row * 64 + j * 16 + l15] = f2b(acc[i][j][r] * dv);
      }
    }
}

// ------- aggregate (round-1 structure): one wave per node, registers --------
// hbf is PRE-SCALED (hs = h*dinv[src]); massive TLP (25k blocks) hides latency
__global__ __launch_bounds__(256) void agg_kernel(const unsigned short* __restrict__ hbf,
                                                  const int* __restrict__ rowptr,
                                                  const int* __restrict__ csr_src,
                                                  const float* __restrict__ dinv,
                                                  const float* __restrict__ b_gcn,
                                                  const float* __restrict__ W_cls,
                                                  const float* __restrict__ b_cls,
                                                  float* __restrict__ out, int n) {
  const int lane = threadIdx.x & 63;
  const int node = blockIdx.x * 4 + (threadIdx.x >> 6);
  if (node >= n) return;

  const float dn = dinv[node];
  float inner = 0.f;
  const int e0 = rowptr[node], e1 = rowptr[node + 1];
  int e = e0;
  for (; e + 4 <= e1; e += 4) {
    int s0 = csr_src[e], s1 = csr_src[e + 1], s2 = csr_src[e + 2], s3 = csr_src[e + 3];
    float v0 = b2f(hbf[(size_t)s0 * 64 + lane]);
    float v1 = b2f(hbf[(size_t)s1 * 64 + lane]);
    float v2 = b2f(hbf[(size_t)s2 * 64 + lane]);
    float v3 = b2f(hbf[(size_t)s3 * 64 + lane]);
    inner += (v0 + v1) + (v2 + v3);
  }
  for (; e < e1; ++e) {
    int s = csr_src[e];
    inner += b2f(hbf[(size_t)s * 64 + lane]);
  }
  float self = b2f(hbf[(size_t)node * 64 + lane]);   // h[n]*dinv[n]
  float h2 = fmaf(dn, inner + self, b_gcn[lane]);
  h2 = h2 > 0.f ? h2 : 0.f;

  float p[7];
#pragma unroll
  for (int c = 0; c < 7; ++c) p[c] = h2 * W_cls[lane * 7 + c];
#pragma unroll
  for (int off = 32; off; off >>= 1) {
#pragma unroll
    for (int c = 0; c < 7; ++c) p[c] += __shfl_xor(p[c], off, 64);
  }
  if (lane == 0) {
    float* o = out + (size_t)node * 7;
#pragma unroll
    for (int c = 0; c < 7; ++c) o[c] = p[c] + b_cls[c];
  }
}

extern "C" void kernel_launch(void* const* d_in, const int* in_sizes, int n_in,
                              void* d_out, int out_size, void* d_ws, size_t ws_size,
                              hipStream_t stream) {
  const float* x = (const float*)d_in[0];
  const int* ew = (const int*)d_in[1];
  const float* W_gcn = (const float*)d_in[2];
  const float* b_gcn = (const float*)d_in[3];
  const float* W_cls = (const float*)d_in[4];
  const float* b_cls = (const float*)d_in[5];
  float* out = (float*)d_out;

  const int N = in_sizes[0] / 512;              // 100000
  const int NE = in_sizes[1] / 2;               // 3200000

  // try ng=8 (XCD-sharded), fall back to ng=1 if workspace is tight
  int ng = 8;
  size_t off = 0;
  char* ws = (char*)d_ws;
  int* flag; unsigned short* Wt; float* dinv; unsigned short* hbf;
  int* deg8; int* edeg; int* rowptr; int* cursor; int* csr_src; int* part;
  for (int attempt = 0; attempt < 2; ++attempt) {
    off = 0;
    auto take = [&](size_t b) { size_t o = off; off += (b + 255) & ~(size_t)255; return o; };
    flag    = (int*)(ws + take(sizeof(int)));
    Wt      = (unsigned short*)(ws + take((size_t)512 * 64 * 2));
    dinv    = (float*)(ws + take((size_t)N * 4));
    hbf     = (unsigned short*)(ws + take((size_t)N * 64 * 2));
    deg8    = (int*)(ws + take((size_t)ng * N * 4));
    edeg    = (int*)(ws + take((size_t)N * 4));
    rowptr  = (int*)(ws + take(((size_t)N + 1) * 4));
    cursor  = (int*)(ws + take((size_t)N * 4));
    csr_src = (int*)(ws + take((size_t)NE * 4));
    part    = (int*)(ws + take((size_t)512 * 4));
    if (off <= ws_size) break;
    ng = 1;
  }

  const int nbN = (N + 255) / 256;              // 391
  const int nbE = (NE + 255) / 256;             // 12500
  const int sdiv = (N + ng - 1) / ng;           // dst nodes per XCD slice

  detect_kernel<<<1, 64, 0, stream>>>(ew, flag);
  hipMemsetAsync(deg8, 0, (size_t)ng * N * 4, stream);
  deg8_kernel<<<nbE, 256, 0, stream>>>(ew, NE, flag, deg8, N, ng);
  dinvsum_kernel<<<nbN, 256, 0, stream>>>(deg8, dinv, edeg, N, ng);
  partial_kernel<<<nbN, 256, 0, stream>>>(edeg, part, N);
  scanpart_kernel<<<1, 512, 0, stream>>>(part, nbN);
  fill_kernel<<<nbN, 256, 0, stream>>>(edeg, part, rowptr, cursor, N);
  scatter8_kernel<<<nbE * ng, 256, 0, stream>>>(ew, NE, flag, cursor, csr_src, sdiv, ng);
  wt_kernel<<<128, 256, 0, stream>>>(W_gcn, Wt);
  gemm_kernel<<<(N + 127) / 128, 256, 0, stream>>>(x, Wt, dinv, hbf, N);
  agg_kernel<<<(N + 3) / 4, 256, 0, stream>>>(hbf, rowptr, csr_src, dinv,
                                              b_gcn, W_cls, b_cls, out, N);
}